// Round 1
// baseline (950.995 us; speedup 1.0000x reference)
//
#include <hip/hip_runtime.h>
#include <hip/hip_bf16.h>
#include <math.h>

typedef __bf16 bf16_t;
typedef __attribute__((ext_vector_type(8))) __bf16 bf16x8;
typedef __attribute__((ext_vector_type(4))) float f32x4;

// ---------------------------------------------------------------- transpose + f32->bf16: out[c][r] = bf16(in[r][c])
__global__ __launch_bounds__(256) void k_tconv(const float* __restrict__ in, bf16_t* __restrict__ out, int R, int C)
{
    __shared__ float tile[32][33];
    int bc = blockIdx.x * 32;
    int br = blockIdx.y * 32;
    int tx = threadIdx.x & 31, ty = threadIdx.x >> 5;   // 32 x 8
    #pragma unroll
    for (int i = 0; i < 32; i += 8) {
        int r = br + ty + i, c = bc + tx;
        tile[ty + i][tx] = (r < R && c < C) ? in[(long)r * C + c] : 0.f;
    }
    __syncthreads();
    #pragma unroll
    for (int i = 0; i < 32; i += 8) {
        int c = bc + ty + i, r = br + tx;
        if (c < C && r < R) out[(long)c * R + r] = (bf16_t)tile[tx][ty + i];
    }
}

// ---------------------------------------------------------------- CSR build
__global__ __launch_bounds__(256) void k_deg(const int* __restrict__ dst, int* __restrict__ deg, int E)
{
    int e = blockIdx.x * 256 + threadIdx.x;
    if (e < E) atomicAdd(&deg[dst[e]], 1);
}

__global__ __launch_bounds__(1024) void k_scan(const int* __restrict__ deg, int* __restrict__ off,
                                               int* __restrict__ cursor, int n)
{
    __shared__ int wsum[16];
    int t = threadIdx.x, lane = t & 63, wid = t >> 6;
    int base = 0;
    int nchunks = (n + 1023) / 1024;
    for (int ch = 0; ch < nchunks; ch++) {
        int idx = ch * 1024 + t;
        int v = (idx < n) ? deg[idx] : 0;
        int x = v;
        #pragma unroll
        for (int d = 1; d < 64; d <<= 1) { int o = __shfl_up(x, d); if (lane >= d) x += o; }
        if (lane == 63) wsum[wid] = x;
        __syncthreads();
        if (wid == 0 && lane < 16) {
            int y = wsum[lane];
            #pragma unroll
            for (int d = 1; d < 16; d <<= 1) { int o = __shfl_up(y, d); if (lane >= d) y += o; }
            wsum[lane] = y;
        }
        __syncthreads();
        int wbase = (wid == 0) ? 0 : wsum[wid - 1];
        int excl = wbase + x - v;
        if (idx < n) { off[idx] = base + excl; cursor[idx] = base + excl; }
        base += wsum[15];
        __syncthreads();
    }
    if (t == 0) off[n] = base;
}

__global__ __launch_bounds__(256) void k_fill(const int* __restrict__ src, const int* __restrict__ dst,
                                              int* __restrict__ cursor, int* __restrict__ csr, int E)
{
    int e = blockIdx.x * 256 + threadIdx.x;
    if (e < E) {
        int d = dst[e];
        int pos = atomicAdd(&cursor[d], 1);
        csr[pos] = src[e];
    }
}

// ---------------------------------------------------------------- GENConv aggregation: haux = x + segsoftmax-aggr
// one wave per node, 2 channels/lane, single-pass online softmax over incoming edges
__global__ __launch_bounds__(256) void k_agg(const float* __restrict__ X, int ldx,
                                             const int* __restrict__ off, const int* __restrict__ csr,
                                             float* __restrict__ haux,
                                             const float* __restrict__ tptr, int ti, int Nn)
{
    int w = (blockIdx.x * 256 + threadIdx.x) >> 6;
    if (w >= Nn) return;
    int lane = threadIdx.x & 63;
    float t = tptr[ti];
    int e0 = off[w], e1 = off[w + 1];
    float m0 = -__builtin_inff(), m1 = -__builtin_inff();
    float s0 = 0.f, s1 = 0.f, g0 = 0.f, g1 = 0.f;
    for (int e = e0; e < e1; e++) {
        int s = csr[e];
        float2 xv = *(const float2*)(X + (long)s * ldx + lane * 2);
        float msg0 = fmaxf(xv.x, 0.f) + 1e-7f;
        float msg1 = fmaxf(xv.y, 0.f) + 1e-7f;
        float v0 = msg0 * t, v1 = msg1 * t;
        if (v0 > m0) { float sc = __expf(m0 - v0); s0 *= sc; g0 *= sc; m0 = v0; }
        float p0 = __expf(v0 - m0); s0 += p0; g0 += msg0 * p0;
        if (v1 > m1) { float sc = __expf(m1 - v1); s1 *= sc; g1 *= sc; m1 = v1; }
        float p1 = __expf(v1 - m1); s1 += p1; g1 += msg1 * p1;
    }
    float a0 = g0 / (s0 + 1e-16f);
    float a1 = g1 / (s1 + 1e-16f);
    float2 xr = *(const float2*)(X + (long)w * ldx + lane * 2);
    float* outp = haux + (long)w * 128 + lane * 2;
    outp[0] = xr.x + a0;
    outp[1] = xr.y + a1;
}

// ---------------------------------------------------------------- GEMM: C[M,N] = act(A[M,K] @ BT[N,K]^T + bias)
// EPI: 0 = f32 store, 1 = f32 relu store, 2 = bf16 tanh store, 3 = bf16 relu store,
//      4 = attention score: s[row] += sum_col sigmoid(acc+bias)*abuf[row,col]*cw[col]
// ABF16: A operand dtype (0 = f32 converted on the fly, 1 = bf16)
template<int EPI, int ABF16>
__global__ __launch_bounds__(256) void k_gemm(const void* __restrict__ Aptr, int lda,
                                              const bf16_t* __restrict__ BT,
                                              const float* __restrict__ bias,
                                              void* __restrict__ Cout, int ldc,
                                              int M, int N, int K,
                                              const bf16_t* __restrict__ abuf,
                                              const float* __restrict__ cw,
                                              float* __restrict__ sout)
{
    __shared__ __align__(16) bf16_t lA[128 * 64];
    __shared__ __align__(16) bf16_t lB[128 * 64];
    const int tid = threadIdx.x;
    const int m0 = blockIdx.x * 128;
    const int n0 = blockIdx.y * 128;
    const int lane = tid & 63, wid = tid >> 6;
    const int wr = wid >> 1, wc = wid & 1;
    const int lrow = lane & 15, kg = lane >> 4;

    f32x4 acc[4][4];
    #pragma unroll
    for (int i = 0; i < 4; i++)
        #pragma unroll
        for (int j = 0; j < 4; j++)
            #pragma unroll
            for (int r = 0; r < 4; r++) acc[i][j][r] = 0.f;

    const int sRow = tid >> 3;  // 0..31
    const int sK8  = tid & 7;   // 0..7 (16B slot in 64-wide K)

    for (int k0 = 0; k0 < K; k0 += 64) {
        #pragma unroll
        for (int p = 0; p < 4; p++) {
            int row = p * 32 + sRow;
            int grow = m0 + row;
            bf16x8 v;
            if (grow < M) {
                if (ABF16) {
                    v = *(const bf16x8*)((const bf16_t*)Aptr + (long)grow * lda + k0 + sK8 * 8);
                } else {
                    const float* srcp = (const float*)Aptr + (long)grow * lda + k0 + sK8 * 8;
                    f32x4 f0 = *(const f32x4*)srcp;
                    f32x4 f1 = *(const f32x4*)(srcp + 4);
                    #pragma unroll
                    for (int j = 0; j < 4; j++) { v[j] = (bf16_t)f0[j]; v[4 + j] = (bf16_t)f1[j]; }
                }
            } else {
                #pragma unroll
                for (int j = 0; j < 8; j++) v[j] = (bf16_t)0.f;
            }
            int slot = (row * 8 + sK8) ^ (row & 7);   // XOR swizzle (G4): kills 16-way ds_read conflict
            *(bf16x8*)&lA[slot * 8] = v;
        }
        #pragma unroll
        for (int p = 0; p < 4; p++) {
            int row = p * 32 + sRow;
            bf16x8 v = *(const bf16x8*)(BT + (long)(n0 + row) * K + k0 + sK8 * 8);
            int slot = (row * 8 + sK8) ^ (row & 7);
            *(bf16x8*)&lB[slot * 8] = v;
        }
        __syncthreads();
        #pragma unroll
        for (int ks = 0; ks < 2; ks++) {
            int k8 = ks * 4 + kg;
            bf16x8 af[4], bfv[4];
            #pragma unroll
            for (int m = 0; m < 4; m++) {
                int r = wr * 64 + m * 16 + lrow;
                af[m] = *(const bf16x8*)&lA[((r * 8 + k8) ^ (r & 7)) * 8];
            }
            #pragma unroll
            for (int n = 0; n < 4; n++) {
                int r = wc * 64 + n * 16 + lrow;
                bfv[n] = *(const bf16x8*)&lB[((r * 8 + k8) ^ (r & 7)) * 8];
            }
            #pragma unroll
            for (int m = 0; m < 4; m++)
                #pragma unroll
                for (int n = 0; n < 4; n++)
                    acc[m][n] = __builtin_amdgcn_mfma_f32_16x16x32_bf16(af[m], bfv[n], acc[m][n], 0, 0, 0);
        }
        __syncthreads();
    }

    if (EPI == 4) {
        #pragma unroll
        for (int m = 0; m < 4; m++) {
            #pragma unroll
            for (int r = 0; r < 4; r++) {
                int row = m0 + wr * 64 + m * 16 + kg * 4 + r;   // C/D layout: row=(lane>>4)*4+reg
                if (row < M) {
                    float val = 0.f;
                    #pragma unroll
                    for (int n = 0; n < 4; n++) {
                        int col = n0 + wc * 64 + n * 16 + lrow;  // col = lane&15
                        float xv = acc[m][n][r] + bias[col];
                        float sg = 1.f / (1.f + __expf(-xv));
                        float av = (float)abuf[(long)row * N + col];
                        val += sg * av * cw[col];
                    }
                    #pragma unroll
                    for (int o = 1; o < 16; o <<= 1) val += __shfl_xor(val, o);
                    if (lrow == 0) atomicAdd(&sout[row], val);
                }
            }
        }
    } else {
        #pragma unroll
        for (int m = 0; m < 4; m++) {
            #pragma unroll
            for (int r = 0; r < 4; r++) {
                int row = m0 + wr * 64 + m * 16 + kg * 4 + r;
                if (row >= M) continue;
                #pragma unroll
                for (int n = 0; n < 4; n++) {
                    int col = n0 + wc * 64 + n * 16 + lrow;
                    float xv = acc[m][n][r] + bias[col];
                    if (EPI == 1 || EPI == 3) xv = fmaxf(xv, 0.f);
                    if (EPI == 2) xv = tanhf(xv);
                    if (EPI == 0 || EPI == 1) ((float*)Cout)[(long)row * ldc + col] = xv;
                    else                      ((bf16_t*)Cout)[(long)row * ldc + col] = (bf16_t)xv;
                }
            }
        }
    }
}

// ---------------------------------------------------------------- LayerNorm(256) + relu, in place. one wave per row
__global__ __launch_bounds__(256) void k_ln_relu_256(float* __restrict__ buf, const float* __restrict__ w,
                                                     const float* __restrict__ b, int Mrows)
{
    int wid = threadIdx.x >> 6, lane = threadIdx.x & 63;
    int row = blockIdx.x * 4 + wid;
    if (row >= Mrows) return;
    float* p = buf + (long)row * 256;
    f32x4 v = *(const f32x4*)(p + lane * 4);
    float s1 = v[0] + v[1] + v[2] + v[3];
    float s2 = v[0] * v[0] + v[1] * v[1] + v[2] * v[2] + v[3] * v[3];
    #pragma unroll
    for (int o = 32; o >= 1; o >>= 1) { s1 += __shfl_xor(s1, o); s2 += __shfl_xor(s2, o); }
    float mu = s1 * (1.f / 256.f);
    float var = s2 * (1.f / 256.f) - mu * mu;
    float rstd = rsqrtf(var + 1e-5f);
    #pragma unroll
    for (int j = 0; j < 4; j++) {
        int c = lane * 4 + j;
        v[j] = fmaxf((v[j] - mu) * rstd * w[c] + b[c], 0.f);
    }
    *(f32x4*)(p + lane * 4) = v;
}

// ---------------------------------------------------------------- x_new = x_prev + relu(LN128(h)); writes into x_cat
__global__ __launch_bounds__(256) void k_resln_128(const float* __restrict__ hin,
                                                   const float* __restrict__ w, const float* __restrict__ b,
                                                   float* __restrict__ xcat, int coff_src, int coff_dst, int Mrows)
{
    int wid = threadIdx.x >> 6, lane = threadIdx.x & 63;
    int row = blockIdx.x * 4 + wid;
    if (row >= Mrows) return;
    float2 v = *(const float2*)(hin + (long)row * 128 + lane * 2);
    float s1 = v.x + v.y, s2 = v.x * v.x + v.y * v.y;
    #pragma unroll
    for (int o = 32; o >= 1; o >>= 1) { s1 += __shfl_xor(s1, o); s2 += __shfl_xor(s2, o); }
    float mu = s1 * (1.f / 128.f);
    float var = s2 * (1.f / 128.f) - mu * mu;
    float rstd = rsqrtf(var + 1e-5f);
    int c0 = lane * 2;
    float y0 = fmaxf((v.x - mu) * rstd * w[c0] + b[c0], 0.f);
    float y1 = fmaxf((v.y - mu) * rstd * w[c0 + 1] + b[c0 + 1], 0.f);
    const float* xp = xcat + (long)row * 512 + coff_src + c0;
    float* xo = xcat + (long)row * 512 + coff_dst + c0;
    xo[0] = xp[0] + y0;
    xo[1] = xp[1] + y1;
}

// ---------------------------------------------------------------- softmax stats over s[N]
__global__ __launch_bounds__(1024) void k_sred(const float* __restrict__ sN, int Nn, float* __restrict__ red)
{
    __shared__ float lds[1024];
    int t = threadIdx.x;
    float m = -__builtin_inff();
    for (int i = t; i < Nn; i += 1024) m = fmaxf(m, sN[i]);
    lds[t] = m; __syncthreads();
    for (int o = 512; o >= 1; o >>= 1) { if (t < o) lds[t] = fmaxf(lds[t], lds[t + o]); __syncthreads(); }
    m = lds[0]; __syncthreads();
    float s = 0.f;
    for (int i = t; i < Nn; i += 1024) s += __expf(sN[i] - m);
    lds[t] = s; __syncthreads();
    for (int o = 512; o >= 1; o >>= 1) { if (t < o) lds[t] += lds[t + o]; __syncthreads(); }
    if (t == 0) { red[0] = m; red[1] = lds[0]; }
}

// ---------------------------------------------------------------- hp[512] = sum_n softmax(s)[n] * h[n,:]
__global__ __launch_bounds__(512) void k_pool(const bf16_t* __restrict__ h, const float* __restrict__ sN,
                                              const float* __restrict__ red, float* __restrict__ hp, int Nn)
{
    int t = threadIdx.x;
    float m = red[0], inv = 1.f / red[1];
    float acc = 0.f;
    for (int n = blockIdx.x; n < Nn; n += gridDim.x) {
        float wgt = __expf(sN[n] - m) * inv;
        acc += wgt * (float)h[(long)n * 512 + t];
    }
    atomicAdd(&hp[t], acc);
}

// ---------------------------------------------------------------- logits = relu(hp@rho+rb) @ cls + cb
__global__ __launch_bounds__(512) void k_tail(const float* __restrict__ hp,
                                              const float* __restrict__ rho_w, const float* __restrict__ rho_b,
                                              const float* __restrict__ cls_w, const float* __restrict__ cls_b,
                                              float* __restrict__ out)
{
    __shared__ float h1[512], h2[512];
    int t = threadIdx.x;
    h1[t] = hp[t];
    __syncthreads();
    float acc = rho_b[t];
    for (int k = 0; k < 512; k++) acc += h1[k] * rho_w[k * 512 + t];
    h2[t] = fmaxf(acc, 0.f);
    __syncthreads();
    if (t < 4) {
        float a = cls_b[t];
        for (int d = 0; d < 512; d++) a += h2[d] * cls_w[d * 4 + t];
        out[t] = a;
    }
}

// ================================================================ host
extern "C" void kernel_launch(void* const* d_in, const int* in_sizes, int n_in,
                              void* d_out, int out_size, void* d_ws, size_t ws_size,
                              hipStream_t stream)
{
    const float* x       = (const float*)d_in[0];
    const int*   eidx    = (const int*)  d_in[1];   // [2,E]: row 0 = src, row 1 = dst
    const float* fc_w    = (const float*)d_in[2];
    const float* fc_b    = (const float*)d_in[3];
    const float* conv_w1 = (const float*)d_in[4];
    const float* conv_b1 = (const float*)d_in[5];
    const float* conv_lnw= (const float*)d_in[6];
    const float* conv_lnb= (const float*)d_in[7];
    const float* conv_w2 = (const float*)d_in[8];
    const float* conv_b2 = (const float*)d_in[9];
    const float* conv_t  = (const float*)d_in[10];
    const float* norm_w  = (const float*)d_in[11];
    const float* norm_b  = (const float*)d_in[12];
    const float* phi_w   = (const float*)d_in[13];
    const float* phi_b   = (const float*)d_in[14];
    const float* aw      = (const float*)d_in[15];
    const float* ab      = (const float*)d_in[16];
    const float* bw      = (const float*)d_in[17];
    const float* bb      = (const float*)d_in[18];
    const float* cwp     = (const float*)d_in[19];
    // d_in[20] = attn_c_b: constant shift before softmax -> cancels, unused
    const float* rho_w   = (const float*)d_in[21];
    const float* rho_b   = (const float*)d_in[22];
    const float* cls_w   = (const float*)d_in[23];
    const float* cls_b   = (const float*)d_in[24];

    const int Nn = in_sizes[0] / 1024;
    const int E  = in_sizes[1] / 2;

    char* p = (char*)d_ws;
    auto carve = [&](size_t bytes) { char* r = p; p += (bytes + 255) & ~(size_t)255; return r; };

    float*  x_cat = (float*)carve((size_t)Nn * 512 * 4);           // [N,512] f32: x1|xl0|xl1|xl2
    char*   reg1  = carve((size_t)Nn * 256 * 4);                   // tmp1 f32[N,256]  / a_buf bf16[N,512]
    char*   reg2  = carve((size_t)Nn * 256 * 4);                   // haux+conv_out    / h_phi bf16[N,512]
    float*  tmp1     = (float*)reg1;
    bf16_t* a_buf    = (bf16_t*)reg1;
    float*  haux     = (float*)reg2;                               // [N,128]
    float*  conv_out = (float*)(reg2 + (size_t)Nn * 128 * 4);      // [N,128]
    bf16_t* h_phi    = (bf16_t*)reg2;                              // [N,512]
    bf16_t* fcT  = (bf16_t*)carve((size_t)128 * 1024 * 2);
    bf16_t* w1T  = (bf16_t*)carve((size_t)3 * 256 * 128 * 2);
    bf16_t* w2T  = (bf16_t*)carve((size_t)3 * 128 * 256 * 2);
    bf16_t* phiT = (bf16_t*)carve((size_t)512 * 512 * 2);
    bf16_t* aT   = (bf16_t*)carve((size_t)512 * 512 * 2);
    bf16_t* bT   = (bf16_t*)carve((size_t)512 * 512 * 2);
    int*   deg    = (int*)carve((size_t)Nn * 4);
    int*   offArr = (int*)carve((size_t)(Nn + 1) * 4);
    int*   cursor = (int*)carve((size_t)Nn * 4);
    int*   csr    = (int*)carve((size_t)E * 4);
    float* sN     = (float*)carve((size_t)Nn * 4);
    float* red    = (float*)carve(64);
    float* hp     = (float*)carve(512 * 4);

    hipMemsetAsync(deg, 0, (size_t)Nn * 4, stream);
    hipMemsetAsync(sN, 0, (size_t)Nn * 4, stream);
    hipMemsetAsync(hp, 0, 512 * 4, stream);

    // weight transpose+convert (once per launch; tiny)
    k_tconv<<<dim3(4, 32), 256, 0, stream>>>(fc_w, fcT, 1024, 128);
    for (int i = 0; i < 3; i++) {
        k_tconv<<<dim3(8, 4), 256, 0, stream>>>(conv_w1 + (size_t)i * 128 * 256, w1T + (size_t)i * 256 * 128, 128, 256);
        k_tconv<<<dim3(4, 8), 256, 0, stream>>>(conv_w2 + (size_t)i * 256 * 128, w2T + (size_t)i * 128 * 256, 256, 128);
    }
    k_tconv<<<dim3(16, 16), 256, 0, stream>>>(phi_w, phiT, 512, 512);
    k_tconv<<<dim3(16, 16), 256, 0, stream>>>(aw, aT, 512, 512);
    k_tconv<<<dim3(16, 16), 256, 0, stream>>>(bw, bT, 512, 512);

    // CSR build
    k_deg<<<(E + 255) / 256, 256, 0, stream>>>(eidx + E, deg, E);
    k_scan<<<1, 1024, 0, stream>>>(deg, offArr, cursor, Nn);
    k_fill<<<(E + 255) / 256, 256, 0, stream>>>(eidx, eidx + E, cursor, csr, E);

    const int MT  = (Nn + 127) / 128;
    const int agB = (Nn + 3) / 4;

    // fc: x1 = relu(x @ fc_w + fc_b) -> x_cat[:, 0:128]
    k_gemm<1, 0><<<dim3(MT, 1), 256, 0, stream>>>(x, 1024, fcT, fc_b, x_cat, 512, Nn, 128, 1024, nullptr, nullptr, nullptr);

    for (int i = 0; i < 3; i++) {
        const float* xin = x_cat + 128 * i;
        k_agg<<<agB, 256, 0, stream>>>(xin, 512, offArr, csr, haux, conv_t, i, Nn);
        k_gemm<0, 0><<<dim3(MT, 2), 256, 0, stream>>>(haux, 128, w1T + (size_t)i * 256 * 128, conv_b1 + i * 256,
                                                      tmp1, 256, Nn, 256, 128, nullptr, nullptr, nullptr);
        k_ln_relu_256<<<agB, 256, 0, stream>>>(tmp1, conv_lnw + i * 256, conv_lnb + i * 256, Nn);
        if (i == 0) {
            // layer 0: conv output goes straight into x_cat[:,128:256]
            k_gemm<0, 0><<<dim3(MT, 1), 256, 0, stream>>>(tmp1, 256, w2T, conv_b2, x_cat + 128, 512, Nn, 128, 256,
                                                          nullptr, nullptr, nullptr);
        } else {
            k_gemm<0, 0><<<dim3(MT, 1), 256, 0, stream>>>(tmp1, 256, w2T + (size_t)i * 128 * 256, conv_b2 + i * 128,
                                                          conv_out, 128, Nn, 128, 256, nullptr, nullptr, nullptr);
            k_resln_128<<<agB, 256, 0, stream>>>(conv_out, norm_w + i * 128, norm_b + i * 128,
                                                 x_cat, 128 * i, 128 * (i + 1), Nn);
        }
    }

    // head
    k_gemm<3, 0><<<dim3(MT, 4), 256, 0, stream>>>(x_cat, 512, phiT, phi_b, h_phi, 512, Nn, 512, 512, nullptr, nullptr, nullptr);
    k_gemm<2, 1><<<dim3(MT, 4), 256, 0, stream>>>(h_phi, 512, aT, ab, a_buf, 512, Nn, 512, 512, nullptr, nullptr, nullptr);
    k_gemm<4, 1><<<dim3(MT, 4), 256, 0, stream>>>(h_phi, 512, bT, bb, nullptr, 0, Nn, 512, 512, a_buf, cwp, sN);
    k_sred<<<1, 1024, 0, stream>>>(sN, Nn, red);
    k_pool<<<256, 512, 0, stream>>>(h_phi, sN, red, hp, Nn);
    k_tail<<<1, 512, 0, stream>>>(hp, rho_w, rho_b, cls_w, cls_b, (float*)d_out);
}

// Round 2
// 889.489 us; speedup vs baseline: 1.0691x; 1.0691x over previous
//
#include <hip/hip_runtime.h>
#include <hip/hip_bf16.h>
#include <math.h>

typedef __bf16 bf16_t;
typedef __attribute__((ext_vector_type(8))) __bf16 bf16x8;
typedef __attribute__((ext_vector_type(4))) __bf16 bf16x4;
typedef __attribute__((ext_vector_type(2))) __bf16 bf16x2;
typedef __attribute__((ext_vector_type(4))) float f32x4;

// async global->LDS, 16B per lane. dst must be the wave-uniform base (HW adds lane*16).
__device__ __forceinline__ void gld_lds16(const void* g, void* s) {
    __builtin_amdgcn_global_load_lds(
        (__attribute__((address_space(1))) unsigned int*)g,
        (__attribute__((address_space(3))) unsigned int*)s,
        16, 0, 0);
}

// ---------------------------------------------------------------- transpose + f32->bf16: out[c][r] = bf16(in[r][c])
__global__ __launch_bounds__(256) void k_tconv(const float* __restrict__ in, bf16_t* __restrict__ out, int R, int C)
{
    __shared__ float tile[32][33];
    int bc = blockIdx.x * 32;
    int br = blockIdx.y * 32;
    int tx = threadIdx.x & 31, ty = threadIdx.x >> 5;   // 32 x 8
    #pragma unroll
    for (int i = 0; i < 32; i += 8) {
        int r = br + ty + i, c = bc + tx;
        tile[ty + i][tx] = (r < R && c < C) ? in[(long)r * C + c] : 0.f;
    }
    __syncthreads();
    #pragma unroll
    for (int i = 0; i < 32; i += 8) {
        int c = bc + ty + i, r = br + tx;
        if (c < C && r < R) out[(long)c * R + r] = (bf16_t)tile[tx][ty + i];
    }
}

// ---------------------------------------------------------------- CSR build
__global__ __launch_bounds__(256) void k_deg(const int* __restrict__ dst, int* __restrict__ deg, int E)
{
    int e = blockIdx.x * 256 + threadIdx.x;
    if (e < E) atomicAdd(&deg[dst[e]], 1);
}

__global__ __launch_bounds__(1024) void k_scan(const int* __restrict__ deg, int* __restrict__ off,
                                               int* __restrict__ cursor, int n)
{
    __shared__ int wsum[16];
    int t = threadIdx.x, lane = t & 63, wid = t >> 6;
    int base = 0;
    int nchunks = (n + 1023) / 1024;
    for (int ch = 0; ch < nchunks; ch++) {
        int idx = ch * 1024 + t;
        int v = (idx < n) ? deg[idx] : 0;
        int x = v;
        #pragma unroll
        for (int d = 1; d < 64; d <<= 1) { int o = __shfl_up(x, d); if (lane >= d) x += o; }
        if (lane == 63) wsum[wid] = x;
        __syncthreads();
        if (wid == 0 && lane < 16) {
            int y = wsum[lane];
            #pragma unroll
            for (int d = 1; d < 16; d <<= 1) { int o = __shfl_up(y, d); if (lane >= d) y += o; }
            wsum[lane] = y;
        }
        __syncthreads();
        int wbase = (wid == 0) ? 0 : wsum[wid - 1];
        int excl = wbase + x - v;
        if (idx < n) { off[idx] = base + excl; cursor[idx] = base + excl; }
        base += wsum[15];
        __syncthreads();
    }
    if (t == 0) off[n] = base;
}

__global__ __launch_bounds__(256) void k_fill(const int* __restrict__ src, const int* __restrict__ dst,
                                              int* __restrict__ cursor, int* __restrict__ csr, int E)
{
    int e = blockIdx.x * 256 + threadIdx.x;
    if (e < E) {
        int d = dst[e];
        int pos = atomicAdd(&cursor[d], 1);
        csr[pos] = src[e];
    }
}

// ---------------------------------------------------------------- GENConv aggregation: haux = x + segsoftmax-aggr
// one wave per node, 2 channels/lane, single-pass online softmax over incoming edges. bf16 in, bf16 out.
__global__ __launch_bounds__(256) void k_agg(const bf16_t* __restrict__ X, int ldx,
                                             const int* __restrict__ off, const int* __restrict__ csr,
                                             bf16_t* __restrict__ haux,
                                             const float* __restrict__ tptr, int ti, int Nn)
{
    int w = (blockIdx.x * 256 + threadIdx.x) >> 6;
    if (w >= Nn) return;
    int lane = threadIdx.x & 63;
    float t = tptr[ti];
    int e0 = off[w], e1 = off[w + 1];
    float m0 = -__builtin_inff(), m1 = -__builtin_inff();
    float s0 = 0.f, s1 = 0.f, g0 = 0.f, g1 = 0.f;
    for (int e = e0; e < e1; e++) {
        int s = csr[e];
        bf16x2 xv = *(const bf16x2*)(X + (long)s * ldx + lane * 2);
        float msg0 = fmaxf((float)xv[0], 0.f) + 1e-7f;
        float msg1 = fmaxf((float)xv[1], 0.f) + 1e-7f;
        float v0 = msg0 * t, v1 = msg1 * t;
        if (v0 > m0) { float sc = __expf(m0 - v0); s0 *= sc; g0 *= sc; m0 = v0; }
        float p0 = __expf(v0 - m0); s0 += p0; g0 += msg0 * p0;
        if (v1 > m1) { float sc = __expf(m1 - v1); s1 *= sc; g1 *= sc; m1 = v1; }
        float p1 = __expf(v1 - m1); s1 += p1; g1 += msg1 * p1;
    }
    float a0 = g0 / (s0 + 1e-16f);
    float a1 = g1 / (s1 + 1e-16f);
    bf16x2 xr = *(const bf16x2*)(X + (long)w * ldx + lane * 2);
    bf16_t* outp = haux + (long)w * 128 + lane * 2;
    outp[0] = (bf16_t)((float)xr[0] + a0);
    outp[1] = (bf16_t)((float)xr[1] + a1);
}

// ---------------------------------------------------------------- GEMM: C[M,N] = act(A[M,K] @ BT[N,K]^T + bias)
// EPI: 0 = f32 store
//      3 = bf16 relu store
//      5 = fused attention: s[row] += sum_col tanh(accA+bias)*sigmoid(accB+bias2)*cw[col]
//      6 = dual store: bf16 -> Cout (ldc), f32 -> Cout2 (ldc2)
// ABF16: 1 = A bf16 (async global_load_lds staging), 0 = A f32 (reg-staged convert)
template<int EPI, int ABF16>
__global__ __launch_bounds__(256) void k_gemm(const void* __restrict__ Aptr, int lda,
                                              const bf16_t* __restrict__ BT,
                                              const float* __restrict__ bias,
                                              void* __restrict__ Cout, int ldc,
                                              int M, int N, int K,
                                              const bf16_t* __restrict__ BT2,
                                              const float* __restrict__ bias2,
                                              const float* __restrict__ cw,
                                              float* __restrict__ sout,
                                              float* __restrict__ Cout2, int ldc2)
{
    // LDS layout: linear 16B slots; slot s holds logical (row = s>>3, k8 = (s&7)^(row&7)).
    // Reads use slot ((r*8+k8)^(r&7)) = r*8 + (k8^(r&7))  ==> consistent (rule #21: swizzle
    // lives in the global SOURCE address + the READ, LDS dest stays linear for global_load_lds).
    __shared__ __align__(16) bf16_t lA[128 * 64];
    __shared__ __align__(16) bf16_t lB[128 * 64];
    __shared__ __align__(16) bf16_t lB2[(EPI == 5) ? 128 * 64 : 8];
    const int tid = threadIdx.x;
    const int m0 = blockIdx.x * 128;
    const int n0 = blockIdx.y * 128;
    const int lane = tid & 63, wid = tid >> 6;
    const int wr = wid >> 1, wc = wid & 1;
    const int lrow = lane & 15, kg = lane >> 4;

    f32x4 acc[4][4];
    f32x4 acc2[(EPI == 5) ? 4 : 1][4];
    #pragma unroll
    for (int i = 0; i < 4; i++)
        #pragma unroll
        for (int j = 0; j < 4; j++)
            #pragma unroll
            for (int r = 0; r < 4; r++) acc[i][j][r] = 0.f;
    if constexpr (EPI == 5) {
        #pragma unroll
        for (int i = 0; i < 4; i++)
            #pragma unroll
            for (int j = 0; j < 4; j++)
                #pragma unroll
                for (int r = 0; r < 4; r++) acc2[i][j][r] = 0.f;
    }

    const int sRow = tid >> 3;  // reg-staged f32 path indexing
    const int sK8  = tid & 7;
    const int ubase = tid & 192;  // wave-uniform slot base within a 256-slot chunk

    for (int k0 = 0; k0 < K; k0 += 64) {
        if (ABF16) {
            const bf16_t* Ab = (const bf16_t*)Aptr;
            #pragma unroll
            for (int pp = 0; pp < 4; pp++) {
                int s = pp * 256 + tid;
                int row = s >> 3;
                int k8s = (s & 7) ^ (row & 7);
                int grow = m0 + row;
                if (grow < M)
                    gld_lds16(Ab + (long)grow * lda + k0 + k8s * 8, lA + (pp * 256 + ubase) * 8);
            }
        } else {
            #pragma unroll
            for (int p = 0; p < 4; p++) {
                int row = p * 32 + sRow;
                int grow = m0 + row;
                bf16x8 v;
                if (grow < M) {
                    const float* srcp = (const float*)Aptr + (long)grow * lda + k0 + sK8 * 8;
                    f32x4 f0 = *(const f32x4*)srcp;
                    f32x4 f1 = *(const f32x4*)(srcp + 4);
                    #pragma unroll
                    for (int j = 0; j < 4; j++) { v[j] = (bf16_t)f0[j]; v[4 + j] = (bf16_t)f1[j]; }
                } else {
                    #pragma unroll
                    for (int j = 0; j < 8; j++) v[j] = (bf16_t)0.f;
                }
                int slot = (row * 8 + sK8) ^ (row & 7);
                *(bf16x8*)&lA[slot * 8] = v;
            }
        }
        #pragma unroll
        for (int pp = 0; pp < 4; pp++) {
            int s = pp * 256 + tid;
            int row = s >> 3;
            int k8s = (s & 7) ^ (row & 7);
            gld_lds16(BT + (long)(n0 + row) * K + k0 + k8s * 8, lB + (pp * 256 + ubase) * 8);
            if constexpr (EPI == 5)
                gld_lds16(BT2 + (long)(n0 + row) * K + k0 + k8s * 8, lB2 + (pp * 256 + ubase) * 8);
        }
        __syncthreads();   // compiler drains vmcnt+lgkmcnt here
        #pragma unroll
        for (int ks = 0; ks < 2; ks++) {
            int k8 = ks * 4 + kg;
            bf16x8 af[4], bfv[4];
            #pragma unroll
            for (int m = 0; m < 4; m++) {
                int r = wr * 64 + m * 16 + lrow;
                af[m] = *(const bf16x8*)&lA[((r * 8 + k8) ^ (r & 7)) * 8];
            }
            #pragma unroll
            for (int n = 0; n < 4; n++) {
                int r = wc * 64 + n * 16 + lrow;
                bfv[n] = *(const bf16x8*)&lB[((r * 8 + k8) ^ (r & 7)) * 8];
            }
            #pragma unroll
            for (int m = 0; m < 4; m++)
                #pragma unroll
                for (int n = 0; n < 4; n++)
                    acc[m][n] = __builtin_amdgcn_mfma_f32_16x16x32_bf16(af[m], bfv[n], acc[m][n], 0, 0, 0);
            if constexpr (EPI == 5) {
                bf16x8 bfv2[4];
                #pragma unroll
                for (int n = 0; n < 4; n++) {
                    int r = wc * 64 + n * 16 + lrow;
                    bfv2[n] = *(const bf16x8*)&lB2[((r * 8 + k8) ^ (r & 7)) * 8];
                }
                #pragma unroll
                for (int m = 0; m < 4; m++)
                    #pragma unroll
                    for (int n = 0; n < 4; n++)
                        acc2[m][n] = __builtin_amdgcn_mfma_f32_16x16x32_bf16(af[m], bfv2[n], acc2[m][n], 0, 0, 0);
            }
        }
        __syncthreads();
    }

    if constexpr (EPI == 5) {
        #pragma unroll
        for (int m = 0; m < 4; m++) {
            #pragma unroll
            for (int r = 0; r < 4; r++) {
                int row = m0 + wr * 64 + m * 16 + kg * 4 + r;   // C/D: col=lane&15, row=(lane>>4)*4+reg
                if (row < M) {
                    float val = 0.f;
                    #pragma unroll
                    for (int n = 0; n < 4; n++) {
                        int col = n0 + wc * 64 + n * 16 + lrow;
                        float av = tanhf(acc[m][n][r] + bias[col]);
                        float bv = 1.f / (1.f + __expf(-(acc2[m][n][r] + bias2[col])));
                        val += av * bv * cw[col];
                    }
                    #pragma unroll
                    for (int o = 1; o < 16; o <<= 1) val += __shfl_xor(val, o);
                    if (lrow == 0) atomicAdd(&sout[row], val);
                }
            }
        }
    } else {
        #pragma unroll
        for (int m = 0; m < 4; m++) {
            #pragma unroll
            for (int r = 0; r < 4; r++) {
                int row = m0 + wr * 64 + m * 16 + kg * 4 + r;
                if (row >= M) continue;
                #pragma unroll
                for (int n = 0; n < 4; n++) {
                    int col = n0 + wc * 64 + n * 16 + lrow;
                    float xv = acc[m][n][r] + bias[col];
                    if (EPI == 3) xv = fmaxf(xv, 0.f);
                    if (EPI == 0) ((float*)Cout)[(long)row * ldc + col] = xv;
                    else          ((bf16_t*)Cout)[(long)row * ldc + col] = (bf16_t)xv;
                    if (EPI == 6) Cout2[(long)row * ldc2 + col] = xv;
                }
            }
        }
    }
}

// ---------------------------------------------------------------- LayerNorm(256) + relu: f32 in, bf16 out
__global__ __launch_bounds__(256) void k_ln256(const float* __restrict__ in, const float* __restrict__ w,
                                               const float* __restrict__ b, bf16_t* __restrict__ out, int Mrows)
{
    int wid = threadIdx.x >> 6, lane = threadIdx.x & 63;
    int row = blockIdx.x * 4 + wid;
    if (row >= Mrows) return;
    const float* p = in + (long)row * 256;
    f32x4 v = *(const f32x4*)(p + lane * 4);
    float s1 = v[0] + v[1] + v[2] + v[3];
    float s2 = v[0] * v[0] + v[1] * v[1] + v[2] * v[2] + v[3] * v[3];
    #pragma unroll
    for (int o = 32; o >= 1; o >>= 1) { s1 += __shfl_xor(s1, o); s2 += __shfl_xor(s2, o); }
    float mu = s1 * (1.f / 256.f);
    float var = s2 * (1.f / 256.f) - mu * mu;
    float rstd = rsqrtf(var + 1e-5f);
    bf16x4 o4;
    #pragma unroll
    for (int j = 0; j < 4; j++) {
        int c = lane * 4 + j;
        o4[j] = (bf16_t)fmaxf((v[j] - mu) * rstd * w[c] + b[c], 0.f);
    }
    *(bf16x4*)(out + (long)row * 256 + lane * 4) = o4;
}

// ---------------------------------------------------------------- x_new = x_prev + relu(LN128(h))
// writes bf16 slice of x_cat_b (stride 512) and optional f32 copy (stride 128)
__global__ __launch_bounds__(256) void k_resln(const float* __restrict__ hin,
                                               const float* __restrict__ w, const float* __restrict__ b,
                                               const float* __restrict__ xprev,
                                               bf16_t* __restrict__ xout_b, float* __restrict__ xout_f, int Mrows)
{
    int wid = threadIdx.x >> 6, lane = threadIdx.x & 63;
    int row = blockIdx.x * 4 + wid;
    if (row >= Mrows) return;
    float2 v = *(const float2*)(hin + (long)row * 128 + lane * 2);
    float s1 = v.x + v.y, s2 = v.x * v.x + v.y * v.y;
    #pragma unroll
    for (int o = 32; o >= 1; o >>= 1) { s1 += __shfl_xor(s1, o); s2 += __shfl_xor(s2, o); }
    float mu = s1 * (1.f / 128.f);
    float var = s2 * (1.f / 128.f) - mu * mu;
    float rstd = rsqrtf(var + 1e-5f);
    int c0 = lane * 2;
    float2 xp = *(const float2*)(xprev + (long)row * 128 + c0);
    float x0 = xp.x + fmaxf((v.x - mu) * rstd * w[c0] + b[c0], 0.f);
    float x1 = xp.y + fmaxf((v.y - mu) * rstd * w[c0 + 1] + b[c0 + 1], 0.f);
    bf16x2 ob; ob[0] = (bf16_t)x0; ob[1] = (bf16_t)x1;
    *(bf16x2*)(xout_b + (long)row * 512 + c0) = ob;
    if (xout_f) { float2 of; of.x = x0; of.y = x1; *(float2*)(xout_f + (long)row * 128 + c0) = of; }
}

// ---------------------------------------------------------------- softmax stats over s[N]
__global__ __launch_bounds__(1024) void k_sred(const float* __restrict__ sN, int Nn, float* __restrict__ red)
{
    __shared__ float lds[1024];
    int t = threadIdx.x;
    float m = -__builtin_inff();
    for (int i = t; i < Nn; i += 1024) m = fmaxf(m, sN[i]);
    lds[t] = m; __syncthreads();
    for (int o = 512; o >= 1; o >>= 1) { if (t < o) lds[t] = fmaxf(lds[t], lds[t + o]); __syncthreads(); }
    m = lds[0]; __syncthreads();
    float s = 0.f;
    for (int i = t; i < Nn; i += 1024) s += __expf(sN[i] - m);
    lds[t] = s; __syncthreads();
    for (int o = 512; o >= 1; o >>= 1) { if (t < o) lds[t] += lds[t + o]; __syncthreads(); }
    if (t == 0) { red[0] = m; red[1] = lds[0]; }
}

// ---------------------------------------------------------------- hp[512] = sum_n softmax(s)[n] * h[n,:]
__global__ __launch_bounds__(512) void k_pool(const bf16_t* __restrict__ h, const float* __restrict__ sN,
                                              const float* __restrict__ red, float* __restrict__ hp, int Nn)
{
    int t = threadIdx.x;
    float m = red[0], inv = 1.f / red[1];
    float acc = 0.f;
    for (int n = blockIdx.x; n < Nn; n += gridDim.x) {
        float wgt = __expf(sN[n] - m) * inv;
        acc += wgt * (float)h[(long)n * 512 + t];
    }
    atomicAdd(&hp[t], acc);
}

// ---------------------------------------------------------------- logits = relu(hp@rho+rb) @ cls + cb
__global__ __launch_bounds__(512) void k_tail(const float* __restrict__ hp,
                                              const float* __restrict__ rho_w, const float* __restrict__ rho_b,
                                              const float* __restrict__ cls_w, const float* __restrict__ cls_b,
                                              float* __restrict__ out)
{
    __shared__ float h1[512], h2[512];
    int t = threadIdx.x;
    h1[t] = hp[t];
    __syncthreads();
    float acc = rho_b[t];
    for (int k = 0; k < 512; k++) acc += h1[k] * rho_w[k * 512 + t];
    h2[t] = fmaxf(acc, 0.f);
    __syncthreads();
    if (t < 4) {
        float a = cls_b[t];
        for (int d = 0; d < 512; d++) a += h2[d] * cls_w[d * 4 + t];
        out[t] = a;
    }
}

// ================================================================ host
extern "C" void kernel_launch(void* const* d_in, const int* in_sizes, int n_in,
                              void* d_out, int out_size, void* d_ws, size_t ws_size,
                              hipStream_t stream)
{
    const float* x       = (const float*)d_in[0];
    const int*   eidx    = (const int*)  d_in[1];   // [2,E]: row 0 = src, row 1 = dst
    const float* fc_w    = (const float*)d_in[2];
    const float* fc_b    = (const float*)d_in[3];
    const float* conv_w1 = (const float*)d_in[4];
    const float* conv_b1 = (const float*)d_in[5];
    const float* conv_lnw= (const float*)d_in[6];
    const float* conv_lnb= (const float*)d_in[7];
    const float* conv_w2 = (const float*)d_in[8];
    const float* conv_b2 = (const float*)d_in[9];
    const float* conv_t  = (const float*)d_in[10];
    const float* norm_w  = (const float*)d_in[11];
    const float* norm_b  = (const float*)d_in[12];
    const float* phi_w   = (const float*)d_in[13];
    const float* phi_b   = (const float*)d_in[14];
    const float* aw      = (const float*)d_in[15];
    const float* ab      = (const float*)d_in[16];
    const float* bw      = (const float*)d_in[17];
    const float* bb      = (const float*)d_in[18];
    const float* cwp     = (const float*)d_in[19];
    // d_in[20] = attn_c_b: constant shift before softmax -> cancels, unused
    const float* rho_w   = (const float*)d_in[21];
    const float* rho_b   = (const float*)d_in[22];
    const float* cls_w   = (const float*)d_in[23];
    const float* cls_b   = (const float*)d_in[24];

    const int Nn = in_sizes[0] / 1024;
    const int E  = in_sizes[1] / 2;

    char* p = (char*)d_ws;
    auto carve = [&](size_t bytes) { char* r = p; p += (bytes + 255) & ~(size_t)255; return r; };

    bf16_t* x_cat_b = (bf16_t*)carve((size_t)Nn * 512 * 2);   // [N,512] bf16: x1|xl1|xl2|xl3
    float*  tmp1    = (float*)carve((size_t)Nn * 256 * 4);    // conv MLP hidden, f32
    bf16_t* tmp1b   = (bf16_t*)carve((size_t)Nn * 256 * 2);   // LN+relu output, bf16
    bf16_t* haux    = (bf16_t*)carve((size_t)Nn * 128 * 2);   // agg output, bf16
    float*  conv_out= (float*)carve((size_t)Nn * 128 * 4);    // conv output (layers 1,2), f32
    float*  xs1     = (float*)carve((size_t)Nn * 128 * 4);    // f32 residual chain copies
    float*  xs2     = (float*)carve((size_t)Nn * 128 * 4);
    bf16_t* h_phi   = (bf16_t*)carve((size_t)Nn * 512 * 2);   // [N,512] bf16
    bf16_t* fcT  = (bf16_t*)carve((size_t)128 * 1024 * 2);
    bf16_t* w1T  = (bf16_t*)carve((size_t)3 * 256 * 128 * 2);
    bf16_t* w2T  = (bf16_t*)carve((size_t)3 * 128 * 256 * 2);
    bf16_t* phiT = (bf16_t*)carve((size_t)512 * 512 * 2);
    bf16_t* aT   = (bf16_t*)carve((size_t)512 * 512 * 2);
    bf16_t* bT   = (bf16_t*)carve((size_t)512 * 512 * 2);
    int*   deg    = (int*)carve((size_t)Nn * 4);
    int*   offArr = (int*)carve((size_t)(Nn + 1) * 4);
    int*   cursor = (int*)carve((size_t)Nn * 4);
    int*   csr    = (int*)carve((size_t)E * 4);
    float* sN     = (float*)carve((size_t)Nn * 4);
    float* red    = (float*)carve(64);
    float* hp     = (float*)carve(512 * 4);

    hipMemsetAsync(deg, 0, (size_t)Nn * 4, stream);
    hipMemsetAsync(sN, 0, (size_t)Nn * 4, stream);
    hipMemsetAsync(hp, 0, 512 * 4, stream);

    // weight transpose+convert (tiny)
    k_tconv<<<dim3(4, 32), 256, 0, stream>>>(fc_w, fcT, 1024, 128);
    for (int i = 0; i < 3; i++) {
        k_tconv<<<dim3(8, 4), 256, 0, stream>>>(conv_w1 + (size_t)i * 128 * 256, w1T + (size_t)i * 256 * 128, 128, 256);
        k_tconv<<<dim3(4, 8), 256, 0, stream>>>(conv_w2 + (size_t)i * 256 * 128, w2T + (size_t)i * 128 * 256, 256, 128);
    }
    k_tconv<<<dim3(16, 16), 256, 0, stream>>>(phi_w, phiT, 512, 512);
    k_tconv<<<dim3(16, 16), 256, 0, stream>>>(aw, aT, 512, 512);
    k_tconv<<<dim3(16, 16), 256, 0, stream>>>(bw, bT, 512, 512);

    // CSR build
    k_deg<<<(E + 255) / 256, 256, 0, stream>>>(eidx + E, deg, E);
    k_scan<<<1, 1024, 0, stream>>>(deg, offArr, cursor, Nn);
    k_fill<<<(E + 255) / 256, 256, 0, stream>>>(eidx, eidx + E, cursor, csr, E);

    const int MT  = (Nn + 127) / 128;
    const int agB = (Nn + 3) / 4;

    // fc: x1 = relu(x @ fc_w + fc_b) -> x_cat_b[:, 0:128]  (f32 A, reg-staged)
    k_gemm<3, 0><<<dim3(MT, 1), 256, 0, stream>>>(x, 1024, fcT, fc_b, x_cat_b, 512, Nn, 128, 1024,
                                                  nullptr, nullptr, nullptr, nullptr, nullptr, 0);

    for (int i = 0; i < 3; i++) {
        k_agg<<<agB, 256, 0, stream>>>(x_cat_b + 128 * i, 512, offArr, csr, haux, conv_t, i, Nn);
        k_gemm<0, 1><<<dim3(MT, 2), 256, 0, stream>>>(haux, 128, w1T + (size_t)i * 256 * 128, conv_b1 + i * 256,
                                                      tmp1, 256, Nn, 256, 128,
                                                      nullptr, nullptr, nullptr, nullptr, nullptr, 0);
        k_ln256<<<agB, 256, 0, stream>>>(tmp1, conv_lnw + i * 256, conv_lnb + i * 256, tmp1b, Nn);
        if (i == 0) {
            // layer 0: conv output -> x_cat_b[:,128:256] (bf16) + xs1 (f32 residual source)
            k_gemm<6, 1><<<dim3(MT, 1), 256, 0, stream>>>(tmp1b, 256, w2T, conv_b2, x_cat_b + 128, 512, Nn, 128, 256,
                                                          nullptr, nullptr, nullptr, nullptr, xs1, 128);
        } else {
            k_gemm<0, 1><<<dim3(MT, 1), 256, 0, stream>>>(tmp1b, 256, w2T + (size_t)i * 128 * 256, conv_b2 + i * 128,
                                                          conv_out, 128, Nn, 128, 256,
                                                          nullptr, nullptr, nullptr, nullptr, nullptr, 0);
            k_resln<<<agB, 256, 0, stream>>>(conv_out, norm_w + i * 128, norm_b + i * 128,
                                             (i == 1) ? xs1 : xs2,
                                             x_cat_b + 128 * (i + 1),
                                             (i == 1) ? xs2 : nullptr, Nn);
        }
    }

    // head
    k_gemm<3, 1><<<dim3(MT, 4), 256, 0, stream>>>(x_cat_b, 512, phiT, phi_b, h_phi, 512, Nn, 512, 512,
                                                  nullptr, nullptr, nullptr, nullptr, nullptr, 0);
    // fused attn: s[row] = sum_col tanh(h@aw+ab) * sigmoid(h@bw+bb) * cw[col]
    k_gemm<5, 1><<<dim3(MT, 4), 256, 0, stream>>>(h_phi, 512, aT, ab, nullptr, 0, Nn, 512, 512,
                                                  bT, bb, cwp, sN, nullptr, 0);
    k_sred<<<1, 1024, 0, stream>>>(sN, Nn, red);
    k_pool<<<256, 512, 0, stream>>>(h_phi, sN, red, hp, Nn);
    k_tail<<<1, 512, 0, stream>>>(hp, rho_w, rho_b, cls_w, cls_b, (float*)d_out);
}

// Round 3
// 802.901 us; speedup vs baseline: 1.1844x; 1.1078x over previous
//
#include <hip/hip_runtime.h>
#include <hip/hip_bf16.h>
#include <math.h>

typedef __bf16 bf16_t;
typedef __attribute__((ext_vector_type(8))) __bf16 bf16x8;
typedef __attribute__((ext_vector_type(2))) __bf16 bf16x2;
typedef __attribute__((ext_vector_type(4))) float f32x4;

// async global->LDS, 16B per lane. dst must be the wave-uniform base (HW adds lane*16).
__device__ __forceinline__ void gld_lds16(const void* g, void* s) {
    __builtin_amdgcn_global_load_lds(
        (__attribute__((address_space(1))) unsigned int*)g,
        (__attribute__((address_space(3))) unsigned int*)s,
        16, 0, 0);
}

// bijective XCD chunk swizzle (m204) + col-fast decode: adjacent wg -> same A-stripe
__device__ __forceinline__ int2 sw_decode(int orig, int nwg, int NT) {
    int q = nwg >> 3, r = nwg & 7, xcd = orig & 7, idx = orig >> 3;
    int wg = (xcd < r ? xcd * (q + 1) : r * (q + 1) + (xcd - r) * q) + idx;
    int bx = wg / NT, by = wg - bx * NT;
    return make_int2(bx, by);
}

// ---------------------------------------------------------------- transpose + f32->bf16
// out[((long)c*rs + ro)*R + r] = bf16(in[r*C + c])   (rs/ro: row interleave for B_cat)
__global__ __launch_bounds__(256) void k_tconv(const float* __restrict__ in, bf16_t* __restrict__ out,
                                               int R, int C, int rs, int ro)
{
    __shared__ float tile[32][33];
    int bc = blockIdx.x * 32;
    int br = blockIdx.y * 32;
    int tx = threadIdx.x & 31, ty = threadIdx.x >> 5;   // 32 x 8
    #pragma unroll
    for (int i = 0; i < 32; i += 8) {
        int r = br + ty + i, c = bc + tx;
        tile[ty + i][tx] = (r < R && c < C) ? in[(long)r * C + c] : 0.f;
    }
    __syncthreads();
    #pragma unroll
    for (int i = 0; i < 32; i += 8) {
        int c = bc + ty + i, r = br + tx;
        if (c < C && r < R) out[((long)c * rs + ro) * R + r] = (bf16_t)tile[tx][ty + i];
    }
}

__global__ __launch_bounds__(256) void k_bcat(const float* __restrict__ ab, const float* __restrict__ bb,
                                              float* __restrict__ bc)
{
    int i = blockIdx.x * 256 + threadIdx.x;
    if (i < 512) { bc[2 * i] = ab[i]; bc[2 * i + 1] = bb[i]; }
}

// ---------------------------------------------------------------- CSR build
__global__ __launch_bounds__(256) void k_deg(const int* __restrict__ dst, int* __restrict__ deg, int E)
{
    int e = blockIdx.x * 256 + threadIdx.x;
    if (e < E) atomicAdd(&deg[dst[e]], 1);
}

__global__ __launch_bounds__(1024) void k_scan(const int* __restrict__ deg, int* __restrict__ off,
                                               int* __restrict__ cursor, int n)
{
    __shared__ int wsum[16];
    int t = threadIdx.x, lane = t & 63, wid = t >> 6;
    int base = 0;
    int nchunks = (n + 1023) / 1024;
    for (int ch = 0; ch < nchunks; ch++) {
        int idx = ch * 1024 + t;
        int v = (idx < n) ? deg[idx] : 0;
        int x = v;
        #pragma unroll
        for (int d = 1; d < 64; d <<= 1) { int o = __shfl_up(x, d); if (lane >= d) x += o; }
        if (lane == 63) wsum[wid] = x;
        __syncthreads();
        if (wid == 0 && lane < 16) {
            int y = wsum[lane];
            #pragma unroll
            for (int d = 1; d < 16; d <<= 1) { int o = __shfl_up(y, d); if (lane >= d) y += o; }
            wsum[lane] = y;
        }
        __syncthreads();
        int wbase = (wid == 0) ? 0 : wsum[wid - 1];
        int excl = wbase + x - v;
        if (idx < n) { off[idx] = base + excl; cursor[idx] = base + excl; }
        base += wsum[15];
        __syncthreads();
    }
    if (t == 0) off[n] = base;
}

__global__ __launch_bounds__(256) void k_fill(const int* __restrict__ src, const int* __restrict__ dst,
                                              int* __restrict__ cursor, int* __restrict__ csr, int E)
{
    int e = blockIdx.x * 256 + threadIdx.x;
    if (e < E) {
        int d = dst[e];
        int pos = atomicAdd(&cursor[d], 1);
        csr[pos] = src[e];
    }
}

// ---------------------------------------------------------------- GENConv aggregation (compact bf16 [N,128] in)
__global__ __launch_bounds__(256) void k_agg(const bf16_t* __restrict__ X,
                                             const int* __restrict__ off, const int* __restrict__ csr,
                                             bf16_t* __restrict__ haux,
                                             const float* __restrict__ tptr, int ti, int Nn)
{
    int w = (blockIdx.x * 256 + threadIdx.x) >> 6;
    if (w >= Nn) return;
    int lane = threadIdx.x & 63;
    float t = tptr[ti];
    int e0 = off[w], e1 = off[w + 1];
    float m0 = -__builtin_inff(), m1 = -__builtin_inff();
    float s0 = 0.f, s1 = 0.f, g0 = 0.f, g1 = 0.f;
    for (int e = e0; e < e1; e++) {
        int s = csr[e];
        bf16x2 xv = *(const bf16x2*)(X + (long)s * 128 + lane * 2);
        float msg0 = fmaxf((float)xv[0], 0.f) + 1e-7f;
        float msg1 = fmaxf((float)xv[1], 0.f) + 1e-7f;
        float v0 = msg0 * t, v1 = msg1 * t;
        if (v0 > m0) { float sc = __expf(m0 - v0); s0 *= sc; g0 *= sc; m0 = v0; }
        float p0 = __expf(v0 - m0); s0 += p0; g0 += msg0 * p0;
        if (v1 > m1) { float sc = __expf(m1 - v1); s1 *= sc; g1 *= sc; m1 = v1; }
        float p1 = __expf(v1 - m1); s1 += p1; g1 += msg1 * p1;
    }
    float a0 = g0 / (s0 + 1e-16f);
    float a1 = g1 / (s1 + 1e-16f);
    bf16x2 xr = *(const bf16x2*)(X + (long)w * 128 + lane * 2);
    bf16_t* outp = haux + (long)w * 128 + lane * 2;
    outp[0] = (bf16_t)((float)xr[0] + a0);
    outp[1] = (bf16_t)((float)xr[1] + a1);
}

// ---------------------------------------------------------------- GEMM 128x128 tile
// EPI: 3 = bf16 relu store (+ optional compact bf16 dual store, N must be 128)
//      5 = interleaved attention: B_cat cols 2j/2j+1 = a/b; s[row] += tanh*sigmoid*cw[j]
// ABF16: 1 = A bf16 (async global_load_lds), 0 = A f32 (reg-staged convert)
template<int EPI, int ABF16>
__global__ __launch_bounds__(256) void k_gemm(const void* __restrict__ Aptr, int lda,
                                              const bf16_t* __restrict__ BT,
                                              const float* __restrict__ bias,
                                              void* __restrict__ Cout, int ldc,
                                              bf16_t* __restrict__ Cout2,
                                              int M, int N, int K, int NT,
                                              const float* __restrict__ cw,
                                              float* __restrict__ sout)
{
    __shared__ __align__(16) bf16_t lA[128 * 64];
    __shared__ __align__(16) bf16_t lB[128 * 64];
    int2 bxy = sw_decode(blockIdx.x, gridDim.x, NT);
    const int m0 = bxy.x * 128;
    const int n0 = bxy.y * 128;
    const int tid = threadIdx.x;
    const int lane = tid & 63, wid = tid >> 6;
    const int wr = wid >> 1, wc = wid & 1;
    const int lrow = lane & 15, kg = lane >> 4;

    f32x4 acc[4][4];
    #pragma unroll
    for (int i = 0; i < 4; i++)
        #pragma unroll
        for (int j = 0; j < 4; j++)
            #pragma unroll
            for (int r = 0; r < 4; r++) acc[i][j][r] = 0.f;

    const int sRow = tid >> 3;
    const int sK8  = tid & 7;
    const int ubase = tid & 192;

    for (int k0 = 0; k0 < K; k0 += 64) {
        if (ABF16) {
            const bf16_t* Ab = (const bf16_t*)Aptr;
            #pragma unroll
            for (int pp = 0; pp < 4; pp++) {
                int s = pp * 256 + tid;
                int row = s >> 3;
                int k8s = (s & 7) ^ (row & 7);
                int grow = m0 + row;
                if (grow < M)
                    gld_lds16(Ab + (long)grow * lda + k0 + k8s * 8, lA + (pp * 256 + ubase) * 8);
            }
        } else {
            #pragma unroll
            for (int p = 0; p < 4; p++) {
                int row = p * 32 + sRow;
                int grow = m0 + row;
                bf16x8 v;
                if (grow < M) {
                    const float* srcp = (const float*)Aptr + (long)grow * lda + k0 + sK8 * 8;
                    f32x4 f0 = *(const f32x4*)srcp;
                    f32x4 f1 = *(const f32x4*)(srcp + 4);
                    #pragma unroll
                    for (int j = 0; j < 4; j++) { v[j] = (bf16_t)f0[j]; v[4 + j] = (bf16_t)f1[j]; }
                } else {
                    #pragma unroll
                    for (int j = 0; j < 8; j++) v[j] = (bf16_t)0.f;
                }
                int slot = (row * 8 + sK8) ^ (row & 7);
                *(bf16x8*)&lA[slot * 8] = v;
            }
        }
        #pragma unroll
        for (int pp = 0; pp < 4; pp++) {
            int s = pp * 256 + tid;
            int row = s >> 3;
            int k8s = (s & 7) ^ (row & 7);
            gld_lds16(BT + (long)(n0 + row) * K + k0 + k8s * 8, lB + (pp * 256 + ubase) * 8);
        }
        __syncthreads();
        #pragma unroll
        for (int ks = 0; ks < 2; ks++) {
            int k8 = ks * 4 + kg;
            bf16x8 af[4], bfv[4];
            #pragma unroll
            for (int m = 0; m < 4; m++) {
                int r = wr * 64 + m * 16 + lrow;
                af[m] = *(const bf16x8*)&lA[(r * 8 + (k8 ^ (r & 7))) * 8];
            }
            #pragma unroll
            for (int n = 0; n < 4; n++) {
                int r = wc * 64 + n * 16 + lrow;
                bfv[n] = *(const bf16x8*)&lB[(r * 8 + (k8 ^ (r & 7))) * 8];
            }
            #pragma unroll
            for (int m = 0; m < 4; m++)
                #pragma unroll
                for (int n = 0; n < 4; n++)
                    acc[m][n] = __builtin_amdgcn_mfma_f32_16x16x32_bf16(af[m], bfv[n], acc[m][n], 0, 0, 0);
        }
        __syncthreads();
    }

    if constexpr (EPI == 5) {
        #pragma unroll
        for (int m = 0; m < 4; m++) {
            #pragma unroll
            for (int r = 0; r < 4; r++) {
                int row = m0 + wr * 64 + m * 16 + kg * 4 + r;   // C/D: col=lane&15, row=(lane>>4)*4+reg
                float val = 0.f;
                #pragma unroll
                for (int n = 0; n < 4; n++) {
                    int col = n0 + wc * 64 + n * 16 + lrow;
                    float xv = acc[m][n][r] + bias[col];
                    // even col: tanh(xv)=2*sigmoid(2xv)-1 ; odd col: sigmoid(xv). one exp each.
                    int odd = col & 1;
                    float z = odd ? xv : 2.f * xv;
                    float sg = 1.f / (1.f + __expf(-z));
                    float f = odd ? sg : (2.f * sg - 1.f);
                    float partner = __shfl_xor(f, 1);
                    float prod = f * partner;
                    val += odd ? 0.f : prod * cw[col >> 1];
                }
                #pragma unroll
                for (int o = 1; o < 16; o <<= 1) val += __shfl_xor(val, o);
                if (lrow == 0 && row < M) atomicAdd(&sout[row], val);
            }
        }
    } else {
        #pragma unroll
        for (int m = 0; m < 4; m++) {
            #pragma unroll
            for (int r = 0; r < 4; r++) {
                int row = m0 + wr * 64 + m * 16 + kg * 4 + r;
                if (row >= M) continue;
                #pragma unroll
                for (int n = 0; n < 4; n++) {
                    int col = n0 + wc * 64 + n * 16 + lrow;
                    float xv = fmaxf(acc[m][n][r] + bias[col], 0.f);
                    ((bf16_t*)Cout)[(long)row * ldc + col] = (bf16_t)xv;
                    if (Cout2) Cout2[(long)row * 128 + col] = (bf16_t)xv;
                }
            }
        }
    }
}

// ---------------------------------------------------------------- conv MLP part 1: tmp = relu(LN256(A@w1T^T + b1))
// 512 thr, 8 waves; wave w: rows [w*16, w*16+16) x cols [0,256). LN fully in-wave.
__global__ __launch_bounds__(512) void k_conv1(const bf16_t* __restrict__ A,
                                               const bf16_t* __restrict__ BT,
                                               const float* __restrict__ b1,
                                               const float* __restrict__ lnw, const float* __restrict__ lnb,
                                               bf16_t* __restrict__ out, int M)
{
    __shared__ __align__(16) bf16_t lA[128 * 64];
    __shared__ __align__(16) bf16_t lB[256 * 64];
    int2 bxy = sw_decode(blockIdx.x, gridDim.x, 1);
    const int m0 = bxy.x * 128;
    const int tid = threadIdx.x;
    const int lane = tid & 63, w = tid >> 6;
    const int lrow = lane & 15, kg = lane >> 4;
    const int ub = tid & 448;

    f32x4 acc[16];
    #pragma unroll
    for (int n = 0; n < 16; n++)
        #pragma unroll
        for (int r = 0; r < 4; r++) acc[n][r] = 0.f;

    for (int k0 = 0; k0 < 128; k0 += 64) {
        #pragma unroll
        for (int c = 0; c < 2; c++) {
            int s = c * 512 + tid;
            int row = s >> 3, k8s = (s & 7) ^ (row & 7);
            gld_lds16(A + (long)(m0 + row) * 128 + k0 + k8s * 8, lA + (c * 512 + ub) * 8);
        }
        #pragma unroll
        for (int c = 0; c < 4; c++) {
            int s = c * 512 + tid;
            int row = s >> 3, k8s = (s & 7) ^ (row & 7);
            gld_lds16(BT + (long)row * 128 + k0 + k8s * 8, lB + (c * 512 + ub) * 8);
        }
        __syncthreads();
        #pragma unroll
        for (int ks = 0; ks < 2; ks++) {
            int k8 = ks * 4 + kg;
            int ra = w * 16 + lrow;
            bf16x8 af = *(const bf16x8*)&lA[(ra * 8 + (k8 ^ (ra & 7))) * 8];
            #pragma unroll
            for (int n = 0; n < 16; n++) {
                int rb = n * 16 + lrow;
                bf16x8 bf = *(const bf16x8*)&lB[(rb * 8 + (k8 ^ (rb & 7))) * 8];
                acc[n] = __builtin_amdgcn_mfma_f32_16x16x32_bf16(af, bf, acc[n], 0, 0, 0);
            }
        }
        __syncthreads();
    }
    #pragma unroll
    for (int r = 0; r < 4; r++) {
        int row = m0 + w * 16 + kg * 4 + r;
        float xv[16], s1 = 0.f, s2 = 0.f;
        #pragma unroll
        for (int n = 0; n < 16; n++) {
            int col = n * 16 + lrow;
            xv[n] = acc[n][r] + b1[col];
            s1 += xv[n]; s2 += xv[n] * xv[n];
        }
        #pragma unroll
        for (int o = 1; o < 16; o <<= 1) { s1 += __shfl_xor(s1, o); s2 += __shfl_xor(s2, o); }
        float mu = s1 * (1.f / 256.f);
        float var = s2 * (1.f / 256.f) - mu * mu;
        float rstd = rsqrtf(var + 1e-5f);
        #pragma unroll
        for (int n = 0; n < 16; n++) {
            int col = n * 16 + lrow;
            float y = fmaxf((xv[n] - mu) * rstd * lnw[col] + lnb[col], 0.f);
            out[(long)row * 256 + col] = (bf16_t)y;
        }
    }
}

// ---------------------------------------------------------------- conv MLP part 2: conv = A@w2T^T + b2, then
// MODE 0: y = conv (layer 0);  MODE 1: y = xprev + relu(LN128(conv))
// writes: x_cat_b slice (stride 512), optional f32 xs_out, optional compact bf16 xl_out
template<int MODE>
__global__ __launch_bounds__(256) void k_conv2(const bf16_t* __restrict__ A,
                                               const bf16_t* __restrict__ BT,
                                               const float* __restrict__ b2,
                                               const float* __restrict__ nw, const float* __restrict__ nb,
                                               const float* __restrict__ xs_in,
                                               bf16_t* __restrict__ xcat_out,
                                               float* __restrict__ xs_out, bf16_t* __restrict__ xl_out, int M)
{
    __shared__ __align__(16) bf16_t lA[128 * 64];
    __shared__ __align__(16) bf16_t lB[128 * 64];
    int2 bxy = sw_decode(blockIdx.x, gridDim.x, 1);
    const int m0 = bxy.x * 128;
    const int tid = threadIdx.x;
    const int lane = tid & 63, w = tid >> 6;   // 4 waves: rows [w*32, w*32+32)
    const int lrow = lane & 15, kg = lane >> 4;
    const int ub = tid & 192;

    f32x4 acc[2][8];
    #pragma unroll
    for (int m = 0; m < 2; m++)
        #pragma unroll
        for (int n = 0; n < 8; n++)
            #pragma unroll
            for (int r = 0; r < 4; r++) acc[m][n][r] = 0.f;

    for (int k0 = 0; k0 < 256; k0 += 64) {
        #pragma unroll
        for (int c = 0; c < 4; c++) {
            int s = c * 256 + tid;
            int row = s >> 3, k8s = (s & 7) ^ (row & 7);
            gld_lds16(A + (long)(m0 + row) * 256 + k0 + k8s * 8, lA + (c * 256 + ub) * 8);
        }
        #pragma unroll
        for (int c = 0; c < 4; c++) {
            int s = c * 256 + tid;
            int row = s >> 3, k8s = (s & 7) ^ (row & 7);
            gld_lds16(BT + (long)row * 256 + k0 + k8s * 8, lB + (c * 256 + ub) * 8);
        }
        __syncthreads();
        #pragma unroll
        for (int ks = 0; ks < 2; ks++) {
            int k8 = ks * 4 + kg;
            bf16x8 af[2];
            #pragma unroll
            for (int m = 0; m < 2; m++) {
                int r = w * 32 + m * 16 + lrow;
                af[m] = *(const bf16x8*)&lA[(r * 8 + (k8 ^ (r & 7))) * 8];
            }
            #pragma unroll
            for (int n = 0; n < 8; n++) {
                int rb = n * 16 + lrow;
                bf16x8 bf = *(const bf16x8*)&lB[(rb * 8 + (k8 ^ (rb & 7))) * 8];
                #pragma unroll
                for (int m = 0; m < 2; m++)
                    acc[m][n] = __builtin_amdgcn_mfma_f32_16x16x32_bf16(af[m], bf, acc[m][n], 0, 0, 0);
            }
        }
        __syncthreads();
    }
    #pragma unroll
    for (int m = 0; m < 2; m++) {
        #pragma unroll
        for (int r = 0; r < 4; r++) {
            int row = m0 + w * 32 + m * 16 + kg * 4 + r;
            float xv[8];
            #pragma unroll
            for (int n = 0; n < 8; n++) xv[n] = acc[m][n][r] + b2[n * 16 + lrow];
            if constexpr (MODE == 1) {
                float s1 = 0.f, s2 = 0.f;
                #pragma unroll
                for (int n = 0; n < 8; n++) { s1 += xv[n]; s2 += xv[n] * xv[n]; }
                #pragma unroll
                for (int o = 1; o < 16; o <<= 1) { s1 += __shfl_xor(s1, o); s2 += __shfl_xor(s2, o); }
                float mu = s1 * (1.f / 128.f);
                float var = s2 * (1.f / 128.f) - mu * mu;
                float rstd = rsqrtf(var + 1e-5f);
                #pragma unroll
                for (int n = 0; n < 8; n++) {
                    int col = n * 16 + lrow;
                    xv[n] = xs_in[(long)row * 128 + col] + fmaxf((xv[n] - mu) * rstd * nw[col] + nb[col], 0.f);
                }
            }
            #pragma unroll
            for (int n = 0; n < 8; n++) {
                int col = n * 16 + lrow;
                xcat_out[(long)row * 512 + col] = (bf16_t)xv[n];
                if (xs_out) xs_out[(long)row * 128 + col] = xv[n];
                if (xl_out) xl_out[(long)row * 128 + col] = (bf16_t)xv[n];
            }
        }
    }
}

// ---------------------------------------------------------------- softmax stats over s[N]
__global__ __launch_bounds__(1024) void k_sred(const float* __restrict__ sN, int Nn, float* __restrict__ red)
{
    __shared__ float lds[1024];
    int t = threadIdx.x;
    float m = -__builtin_inff();
    for (int i = t; i < Nn; i += 1024) m = fmaxf(m, sN[i]);
    lds[t] = m; __syncthreads();
    for (int o = 512; o >= 1; o >>= 1) { if (t < o) lds[t] = fmaxf(lds[t], lds[t + o]); __syncthreads(); }
    m = lds[0]; __syncthreads();
    float s = 0.f;
    for (int i = t; i < Nn; i += 1024) s += __expf(sN[i] - m);
    lds[t] = s; __syncthreads();
    for (int o = 512; o >= 1; o >>= 1) { if (t < o) lds[t] += lds[t + o]; __syncthreads(); }
    if (t == 0) { red[0] = m; red[1] = lds[0]; }
}

// ---------------------------------------------------------------- hp[512] = sum_n softmax(s)[n] * h[n,:]
__global__ __launch_bounds__(512) void k_pool(const bf16_t* __restrict__ h, const float* __restrict__ sN,
                                              const float* __restrict__ red, float* __restrict__ hp, int Nn)
{
    int t = threadIdx.x;
    float m = red[0], inv = 1.f / red[1];
    float acc = 0.f;
    for (int n = blockIdx.x; n < Nn; n += gridDim.x) {
        float wgt = __expf(sN[n] - m) * inv;
        acc += wgt * (float)h[(long)n * 512 + t];
    }
    atomicAdd(&hp[t], acc);
}

// ---------------------------------------------------------------- logits = relu(hp@rho+rb) @ cls + cb
__global__ __launch_bounds__(512) void k_tail(const float* __restrict__ hp,
                                              const float* __restrict__ rho_w, const float* __restrict__ rho_b,
                                              const float* __restrict__ cls_w, const float* __restrict__ cls_b,
                                              float* __restrict__ out)
{
    __shared__ float h1[512], h2[512];
    int t = threadIdx.x;
    h1[t] = hp[t];
    __syncthreads();
    float acc = rho_b[t];
    for (int k = 0; k < 512; k++) acc += h1[k] * rho_w[k * 512 + t];
    h2[t] = fmaxf(acc, 0.f);
    __syncthreads();
    if (t < 4) {
        float a = cls_b[t];
        for (int d = 0; d < 512; d++) a += h2[d] * cls_w[d * 4 + t];
        out[t] = a;
    }
}

// ================================================================ host
extern "C" void kernel_launch(void* const* d_in, const int* in_sizes, int n_in,
                              void* d_out, int out_size, void* d_ws, size_t ws_size,
                              hipStream_t stream)
{
    const float* x       = (const float*)d_in[0];
    const int*   eidx    = (const int*)  d_in[1];
    const float* fc_w    = (const float*)d_in[2];
    const float* fc_b    = (const float*)d_in[3];
    const float* conv_w1 = (const float*)d_in[4];
    const float* conv_b1 = (const float*)d_in[5];
    const float* conv_lnw= (const float*)d_in[6];
    const float* conv_lnb= (const float*)d_in[7];
    const float* conv_w2 = (const float*)d_in[8];
    const float* conv_b2 = (const float*)d_in[9];
    const float* conv_t  = (const float*)d_in[10];
    const float* norm_w  = (const float*)d_in[11];
    const float* norm_b  = (const float*)d_in[12];
    const float* phi_w   = (const float*)d_in[13];
    const float* phi_b   = (const float*)d_in[14];
    const float* aw      = (const float*)d_in[15];
    const float* ab      = (const float*)d_in[16];
    const float* bw      = (const float*)d_in[17];
    const float* bb      = (const float*)d_in[18];
    const float* cwp     = (const float*)d_in[19];
    // d_in[20] = attn_c_b: constant pre-softmax shift, cancels
    const float* rho_w   = (const float*)d_in[21];
    const float* rho_b   = (const float*)d_in[22];
    const float* cls_w   = (const float*)d_in[23];
    const float* cls_b   = (const float*)d_in[24];

    const int Nn = in_sizes[0] / 1024;
    const int E  = in_sizes[1] / 2;

    char* p = (char*)d_ws;
    auto carve = [&](size_t bytes) { char* r = p; p += (bytes + 255) & ~(size_t)255; return r; };

    bf16_t* x_cat_b = (bf16_t*)carve((size_t)Nn * 512 * 2);   // [N,512] bf16: x1|xl1|xl2|xl3
    bf16_t* tmp1b   = (bf16_t*)carve((size_t)Nn * 256 * 2);   // conv hidden (post LN+relu), bf16
    bf16_t* haux    = (bf16_t*)carve((size_t)Nn * 128 * 2);   // agg output, bf16
    float*  xs1     = (float*)carve((size_t)Nn * 128 * 4);    // f32 residual chain
    float*  xs2     = (float*)carve((size_t)Nn * 128 * 4);
    bf16_t* xl0     = (bf16_t*)carve((size_t)Nn * 128 * 2);   // compact gather buffers
    bf16_t* xl1     = (bf16_t*)carve((size_t)Nn * 128 * 2);
    bf16_t* xl2     = (bf16_t*)carve((size_t)Nn * 128 * 2);
    bf16_t* h_phi   = (bf16_t*)carve((size_t)Nn * 512 * 2);
    bf16_t* fcT  = (bf16_t*)carve((size_t)128 * 1024 * 2);
    bf16_t* w1T  = (bf16_t*)carve((size_t)3 * 256 * 128 * 2);
    bf16_t* w2T  = (bf16_t*)carve((size_t)3 * 128 * 256 * 2);
    bf16_t* phiT = (bf16_t*)carve((size_t)512 * 512 * 2);
    bf16_t* Bcat = (bf16_t*)carve((size_t)1024 * 512 * 2);    // interleaved a/b weights
    float* bias_cat = (float*)carve(1024 * 4);
    int*   deg    = (int*)carve((size_t)Nn * 4);
    int*   offArr = (int*)carve((size_t)(Nn + 1) * 4);
    int*   cursor = (int*)carve((size_t)Nn * 4);
    int*   csr    = (int*)carve((size_t)E * 4);
    float* sN     = (float*)carve((size_t)Nn * 4);
    float* red    = (float*)carve(64);
    float* hp     = (float*)carve(512 * 4);

    hipMemsetAsync(deg, 0, (size_t)Nn * 4, stream);
    hipMemsetAsync(sN, 0, (size_t)Nn * 4, stream);
    hipMemsetAsync(hp, 0, 512 * 4, stream);

    // weight prep
    k_tconv<<<dim3(4, 32), 256, 0, stream>>>(fc_w, fcT, 1024, 128, 1, 0);
    for (int i = 0; i < 3; i++) {
        k_tconv<<<dim3(8, 4), 256, 0, stream>>>(conv_w1 + (size_t)i * 128 * 256, w1T + (size_t)i * 256 * 128, 128, 256, 1, 0);
        k_tconv<<<dim3(4, 8), 256, 0, stream>>>(conv_w2 + (size_t)i * 256 * 128, w2T + (size_t)i * 128 * 256, 256, 128, 1, 0);
    }
    k_tconv<<<dim3(16, 16), 256, 0, stream>>>(phi_w, phiT, 512, 512, 1, 0);
    k_tconv<<<dim3(16, 16), 256, 0, stream>>>(aw, Bcat, 512, 512, 2, 0);
    k_tconv<<<dim3(16, 16), 256, 0, stream>>>(bw, Bcat, 512, 512, 2, 1);
    k_bcat<<<2, 256, 0, stream>>>(ab, bb, bias_cat);

    // CSR build
    k_deg<<<(E + 255) / 256, 256, 0, stream>>>(eidx + E, deg, E);
    k_scan<<<1, 1024, 0, stream>>>(deg, offArr, cursor, Nn);
    k_fill<<<(E + 255) / 256, 256, 0, stream>>>(eidx, eidx + E, cursor, csr, E);

    const int MT  = (Nn + 127) / 128;
    const int agB = (Nn + 3) / 4;

    // fc: x1 = relu(x @ fc_w + b) -> x_cat_b[:,0:128] + compact xl0
    k_gemm<3, 0><<<MT, 256, 0, stream>>>(x, 1024, fcT, fc_b, x_cat_b, 512, xl0,
                                         Nn, 128, 1024, 1, nullptr, nullptr);

    const bf16_t* xls[3] = {xl0, xl1, xl2};
    for (int i = 0; i < 3; i++) {
        k_agg<<<agB, 256, 0, stream>>>(xls[i], offArr, csr, haux, conv_t, i, Nn);
        k_conv1<<<MT, 512, 0, stream>>>(haux, w1T + (size_t)i * 256 * 128, conv_b1 + i * 256,
                                        conv_lnw + i * 256, conv_lnb + i * 256, tmp1b, Nn);
        if (i == 0)
            k_conv2<0><<<MT, 256, 0, stream>>>(tmp1b, w2T, conv_b2, nullptr, nullptr, nullptr,
                                               x_cat_b + 128, xs1, xl1, Nn);
        else if (i == 1)
            k_conv2<1><<<MT, 256, 0, stream>>>(tmp1b, w2T + (size_t)256 * 128, conv_b2 + 128,
                                               norm_w + 128, norm_b + 128, xs1,
                                               x_cat_b + 256, xs2, xl2, Nn);
        else
            k_conv2<1><<<MT, 256, 0, stream>>>(tmp1b, w2T + (size_t)2 * 256 * 128, conv_b2 + 256,
                                               norm_w + 256, norm_b + 256, xs2,
                                               x_cat_b + 384, nullptr, nullptr, Nn);
    }

    // head
    k_gemm<3, 1><<<MT * 4, 256, 0, stream>>>(x_cat_b, 512, phiT, phi_b, h_phi, 512, nullptr,
                                             Nn, 512, 512, 4, nullptr, nullptr);
    k_gemm<5, 1><<<MT * 8, 256, 0, stream>>>(h_phi, 512, Bcat, bias_cat, nullptr, 0, nullptr,
                                             Nn, 1024, 512, 8, cwp, sN);
    k_sred<<<1, 1024, 0, stream>>>(sN, Nn, red);
    k_pool<<<256, 512, 0, stream>>>(h_phi, sN, red, hp, Nn);
    k_tail<<<1, 512, 0, stream>>>(hp, rho_w, rho_b, cls_w, cls_b, (float*)d_out);
}